// Round 3
// baseline (1485.584 us; speedup 1.0000x reference)
//
#include <hip/hip_runtime.h>

#define N_CODES 512
#define D 32
#define NVEC (8192 * 64)          // 524288 vectors
#define ZQ_ELEMS (NVEC * D)
#define MT 4                      // M-tiles (of 16 vectors) per wave
#define MARGIN_TRIG 1.5e-4f

typedef _Float16 half8 __attribute__((ext_vector_type(8)));
typedef float f32x4 __attribute__((ext_vector_type(4)));

// ws layout: @0 double loss acc; @64 float ww[512] (2048B); @2112 half8 bfrag[32*64] (32768B)
// LDS layout: ww @0 (2048) | bfrag @2048 (32768) | scratch @34816 (4 waves * 64 rows * 16B)
#define STAGE_F4 2176             // (2048+32768)/16

__global__ void vq_prep(const float* __restrict__ cb, float* __restrict__ ww,
                        half8* __restrict__ bfrag, double* __restrict__ lossacc) {
    int gid = blockIdx.x * 256 + threadIdx.x;   // 8 blocks x 256 = 2048
    if (gid == 0) *lossacc = 0.0;
    if (gid >= 2048) return;
    int t = gid >> 6, l = gid & 63;
    int code = t * 16 + (l & 15), koff = (l >> 4) * 8;
    const float* w = cb + (size_t)code * D + koff;
    half8 h;
#pragma unroll
    for (int j = 0; j < 8; ++j) h[j] = (_Float16)(512.0f * w[j]);
    bfrag[t * 64 + l] = h;                      // MFMA B-fragment lane order
    if (koff == 0) {                            // platonic ||w||^2 -> f32
        const float* wr = cb + (size_t)code * D;
        double s = 0.0;
#pragma unroll
        for (int d = 0; d < D; ++d) s = fma((double)wr[d], (double)wr[d], s);
        ww[code] = (float)s;
    }
}

__global__ __launch_bounds__(256, 4) void vq_main(
        const float* __restrict__ z, const float* __restrict__ cbf,
        const float4* __restrict__ stage_src,   // ws+64, 34816 bytes
        const float* __restrict__ c32g,         // ws+64 (ww)
        float* __restrict__ zq, float* __restrict__ idxo,
        double* __restrict__ lossacc) {
    __shared__ __align__(16) char smem[34816 + 4096];
    const int tid = threadIdx.x;

    {   // stage ww + B-fragments into LDS (lane-linear, conflict-free later)
        float4* s4 = (float4*)smem;
#pragma unroll
        for (int i = 0; i < 9; ++i) {
            int k = i * 256 + tid;
            if (k < STAGE_F4) s4[k] = stage_src[k];
        }
    }
    __syncthreads();

    const float* lds_ww = (const float*)smem;
    const char* lds_bf = smem + 2048;
    float4* scratch = (float4*)(smem + 34816);

    const int l = tid & 63, wv = tid >> 6;
    const int g16 = l & 15, kg = l >> 4, koff = kg * 8;
    const int vwave = blockIdx.x * 256 + wv * 64;   // wave owns 64 vectors

    // A fragments: A = fp16(-z/256); with B = fp16(512w): A*B sums to -2 z.w
    half8 A[MT];
#pragma unroll
    for (int mt = 0; mt < MT; ++mt) {
        const float* zp = z + (size_t)(vwave + mt * 16 + g16) * D + koff;
        float4 a0 = *(const float4*)zp;
        float4 a1 = *(const float4*)(zp + 4);
        const float sc = -1.0f / 256.0f;
        A[mt][0] = (_Float16)(a0.x * sc); A[mt][1] = (_Float16)(a0.y * sc);
        A[mt][2] = (_Float16)(a0.z * sc); A[mt][3] = (_Float16)(a0.w * sc);
        A[mt][4] = (_Float16)(a1.x * sc); A[mt][5] = (_Float16)(a1.y * sc);
        A[mt][6] = (_Float16)(a1.z * sc); A[mt][7] = (_Float16)(a1.w * sc);
    }

    float m1[MT][4], m2[MT][4]; int i1[MT][4];
#pragma unroll
    for (int mt = 0; mt < MT; ++mt)
#pragma unroll
        for (int r = 0; r < 4; ++r) { m1[mt][r] = 1e30f; m2[mt][r] = 1e30f; i1[mt][r] = 0; }

#pragma unroll 4
    for (int t = 0; t < 32; ++t) {
        half8 B = *(const half8*)(lds_bf + t * 1024 + l * 16);
        float wwv = lds_ww[t * 16 + g16];
        int nl = t * 16 + g16;
#pragma unroll
        for (int mt = 0; mt < MT; ++mt) {
            f32x4 acc = {wwv, wwv, wwv, wwv};   // C-init = ||w||^2 -> acc = score
            acc = __builtin_amdgcn_mfma_f32_16x16x32_f16(A[mt], B, acc, 0, 0, 0);
#pragma unroll
            for (int r = 0; r < 4; ++r) {
                float s = acc[r];
                m2[mt][r] = fminf(m2[mt][r], fmaxf(s, m1[mt][r]));
                bool c = s < m1[mt][r];
                i1[mt][r] = c ? nl : i1[mt][r];
                m1[mt][r] = fminf(m1[mt][r], s);
            }
        }
    }

    // reduce (m1,m2,i1) across the 16 lanes of each row-group
#pragma unroll
    for (int mt = 0; mt < MT; ++mt)
#pragma unroll
        for (int r = 0; r < 4; ++r) {
            float a1v = m1[mt][r], a2v = m2[mt][r]; int ai = i1[mt][r];
#pragma unroll
            for (int dd = 1; dd <= 8; dd <<= 1) {
                float o1 = __shfl_xor(a1v, dd, 64);
                float o2 = __shfl_xor(a2v, dd, 64);
                int oi = __shfl_xor(ai, dd, 64);
                a2v = fminf(fminf(a2v, o2), fmaxf(a1v, o1));
                bool take = (o1 < a1v) || (o1 == a1v && oi < ai);
                ai = take ? oi : ai;
                a1v = fminf(a1v, o1);
            }
            m1[mt][r] = a1v; m2[mt][r] = a2v; i1[mt][r] = ai;
        }

    // row table: lane 16a+r writes row mt*16+4a+r  (static indexing only)
#pragma unroll
    for (int mt = 0; mt < MT; ++mt)
#pragma unroll
        for (int r = 0; r < 4; ++r)
            if (g16 == r) {
                int row = mt * 16 + 4 * kg + r;
                scratch[wv * 64 + row] =
                    make_float4(m1[mt][r], m2[mt][r], __int_as_float(i1[mt][r]), 0.f);
            }
    __syncthreads();

    // trigger rows: gap <= margin -> exact wave-parallel rescan (round-2 quantized formula)
    float4 my = scratch[wv * 64 + l];
    unsigned long long mask = __ballot((my.y - my.x) <= MARGIN_TRIG);
    while (mask) {
        int row = __builtin_ctzll(mask); mask &= mask - 1;
        int v = vwave + row;
        const float* zv = z + (size_t)v * D;        // uniform addr -> broadcast
        double Ad = 0.0;
#pragma unroll
        for (int q = 0; q < 8; ++q) {
            float4 zz = *(const float4*)(zv + q * 4);
            Ad = fma((double)zz.x, (double)zz.x, Ad);
            Ad = fma((double)zz.y, (double)zz.y, Ad);
            Ad = fma((double)zz.z, (double)zz.z, Ad);
            Ad = fma((double)zz.w, (double)zz.w, Ad);
        }
        float Af = (float)Ad;
        float best = 1e30f; int bi = 0;
#pragma unroll
        for (int j = 0; j < 8; ++j) {
            int c = l * 8 + j;                      // lane-major => index-ordered
            const float* w = cbf + (size_t)c * D;
            double bd = 0.0;
#pragma unroll
            for (int q = 0; q < 8; ++q) {
                float4 zz = *(const float4*)(zv + q * 4);
                float4 wq = *(const float4*)(w + q * 4);
                bd = fma((double)zz.x, (double)wq.x, bd);
                bd = fma((double)zz.y, (double)wq.y, bd);
                bd = fma((double)zz.z, (double)wq.z, bd);
                bd = fma((double)zz.w, (double)wq.w, bd);
            }
            float B32 = (float)bd;
            float dq = __fadd_rn(__fsub_rn(Af, __fmul_rn(2.0f, B32)), c32g[c]);
            if (dq < best) { best = dq; bi = c; }
        }
#pragma unroll
        for (int dd = 1; dd < 64; dd <<= 1) {
            float ob = __shfl_xor(best, dd, 64);
            int obi = __shfl_xor(bi, dd, 64);
            bool take = (ob < best) || (ob == best && obi < bi);
            best = take ? ob : best; bi = take ? obi : bi;
        }
        if (l == 0) ((float*)&scratch[wv * 64 + row])[2] = __int_as_float(bi);
    }
    __syncthreads();

    // epilogue: gather z_q, write idx, loss (z reconstructed from A-frag: z = -256*a)
    double ssd = 0.0;
#pragma unroll
    for (int mt = 0; mt < MT; ++mt) {
        int row = mt * 16 + g16;
        int v = vwave + row;
        int win = __float_as_int(scratch[wv * 64 + row].z);
        const float4* qv = (const float4*)(cbf + (size_t)win * D + koff);
        float4 q0 = qv[0], q1 = qv[1];
        float4* zo = (float4*)(zq + (size_t)v * D + koff);
        zo[0] = q0; zo[1] = q1;
        float ss = 0.f, zj, dj;
        zj = -256.0f * (float)A[mt][0]; dj = zj - q0.x; ss = fmaf(dj, dj, ss);
        zj = -256.0f * (float)A[mt][1]; dj = zj - q0.y; ss = fmaf(dj, dj, ss);
        zj = -256.0f * (float)A[mt][2]; dj = zj - q0.z; ss = fmaf(dj, dj, ss);
        zj = -256.0f * (float)A[mt][3]; dj = zj - q0.w; ss = fmaf(dj, dj, ss);
        zj = -256.0f * (float)A[mt][4]; dj = zj - q1.x; ss = fmaf(dj, dj, ss);
        zj = -256.0f * (float)A[mt][5]; dj = zj - q1.y; ss = fmaf(dj, dj, ss);
        zj = -256.0f * (float)A[mt][6]; dj = zj - q1.z; ss = fmaf(dj, dj, ss);
        zj = -256.0f * (float)A[mt][7]; dj = zj - q1.w; ss = fmaf(dj, dj, ss);
        ssd += (double)ss;
        if (kg == 0) idxo[v] = (float)win;
    }
#pragma unroll
    for (int off = 32; off; off >>= 1) ssd += __shfl_down(ssd, off, 64);
    if (l == 0) atomicAdd(lossacc, ssd);
}

__global__ void vq_final(const double* __restrict__ lossacc,
                         float* __restrict__ loss_out) {
    *loss_out = (float)(1.25 * (*lossacc) / (double)ZQ_ELEMS);
}

extern "C" void kernel_launch(void* const* d_in, const int* in_sizes, int n_in,
                              void* d_out, int out_size, void* d_ws, size_t ws_size,
                              hipStream_t stream) {
    const float* z  = (const float*)d_in[0];
    const float* cb = (const float*)d_in[1];
    float* out  = (float*)d_out;
    float* zq   = out;
    float* idxo = out + ZQ_ELEMS;
    float* loss = out + ZQ_ELEMS + NVEC;
    double* lossacc = (double*)d_ws;
    float*  ww      = (float*)((char*)d_ws + 64);
    half8*  bfrag   = (half8*)((char*)d_ws + 2112);
    const float4* stage_src = (const float4*)((char*)d_ws + 64);

    vq_prep<<<8, 256, 0, stream>>>(cb, ww, bfrag, lossacc);
    vq_main<<<NVEC / 256, 256, 0, stream>>>(z, cb, stage_src, ww, zq, idxo, lossacc);
    vq_final<<<1, 1, 0, stream>>>(lossacc, loss);
}

// Round 4
// 800.812 us; speedup vs baseline: 1.8551x; 1.8551x over previous
//
#include <hip/hip_runtime.h>

#define N_CODES 512
#define D 32
#define NVEC (8192 * 64)          // 524288 vectors
#define ZQ_ELEMS (NVEC * D)
#define MT 4                      // M-tiles (of 16 vectors) per wave
#define MARGIN_TRIG 6e-5f
#define SA (-1.0f / 16.0f)        // A = SA*z   (power of 2, exact)
#define SB (32.0f)                // B = SB*w   -> A*B sums to -2 z.w

typedef _Float16 half8 __attribute__((ext_vector_type(8)));
typedef float f32x4 __attribute__((ext_vector_type(4)));

// ws: @0 double lossacc | @64 float ww[512] | @2112 half8 bfrag[32*64]
#define STAGE_F4 2176             // (2048 + 32768) / 16

__global__ void vq_prep(const float* __restrict__ cb, float* __restrict__ ww,
                        half8* __restrict__ bfrag, double* __restrict__ lossacc) {
    int gid = blockIdx.x * 256 + threadIdx.x;   // 8 x 256 = 2048
    if (gid == 0) *lossacc = 0.0;
    if (gid >= 2048) return;
    int t = gid >> 6, l = gid & 63;
    int code = t * 16 + (l & 15), koff = (l >> 4) * 8;
    const float* w = cb + (size_t)code * D + koff;
    half8 h;
#pragma unroll
    for (int j = 0; j < 8; ++j) h[j] = (_Float16)(SB * w[j]);
    bfrag[t * 64 + l] = h;                      // MFMA B-fragment lane order
    if (koff == 0) {                            // platonic ||w||^2 -> f32
        const float* wr = cb + (size_t)code * D;
        double s = 0.0;
#pragma unroll
        for (int d = 0; d < D; ++d) s = fma((double)wr[d], (double)wr[d], s);
        ww[code] = (float)s;
    }
}

__global__ __launch_bounds__(256, 4) void vq_main(
        const float* __restrict__ z, const float* __restrict__ cbf,
        const float4* __restrict__ stage_src,   // ws+64
        const float* __restrict__ c32g,         // ws+64 (ww)
        float* __restrict__ zq, float* __restrict__ idxo,
        double* __restrict__ lossacc) {
    __shared__ __align__(16) char smem[34816];
    const int tid = threadIdx.x;

    {   // stage ww + B-fragments into LDS
        float4* s4 = (float4*)smem;
#pragma unroll
        for (int i = 0; i < 9; ++i) {
            int k = i * 256 + tid;
            if (k < STAGE_F4) s4[k] = stage_src[k];
        }
    }

    const float* lds_ww = (const float*)smem;
    const char* lds_bf = smem + 2048;
    // after the min loop, bfrag is dead; alias scratch + zz over it
    float4* scratch = (float4*)(smem + 2048);            // [4][64] float4
    float* zzlds = (float*)(smem + 2048 + 4096);         // [4][64] float

    const int l = tid & 63, wv = tid >> 6;
    const int g16 = l & 15, kg = l >> 4, koff = kg * 8;
    const int vwave = blockIdx.x * 256 + wv * 64;        // wave owns 64 vectors

    // A fragments + per-row ||z||^2 partials
    half8 A[MT];
    float zzr[MT];
#pragma unroll
    for (int mt = 0; mt < MT; ++mt) {
        const float* zp = z + (size_t)(vwave + mt * 16 + g16) * D + koff;
        float4 a0 = *(const float4*)zp;
        float4 a1 = *(const float4*)(zp + 4);
        A[mt][0] = (_Float16)(a0.x * SA); A[mt][1] = (_Float16)(a0.y * SA);
        A[mt][2] = (_Float16)(a0.z * SA); A[mt][3] = (_Float16)(a0.w * SA);
        A[mt][4] = (_Float16)(a1.x * SA); A[mt][5] = (_Float16)(a1.y * SA);
        A[mt][6] = (_Float16)(a1.z * SA); A[mt][7] = (_Float16)(a1.w * SA);
        float ss = 0.f;
        ss = fmaf(a0.x, a0.x, ss); ss = fmaf(a0.y, a0.y, ss);
        ss = fmaf(a0.z, a0.z, ss); ss = fmaf(a0.w, a0.w, ss);
        ss = fmaf(a1.x, a1.x, ss); ss = fmaf(a1.y, a1.y, ss);
        ss = fmaf(a1.z, a1.z, ss); ss = fmaf(a1.w, a1.w, ss);
        // sum the 4 koff chunks of this row (lanes differing in bits 4,5)
        ss += __shfl_xor(ss, 16, 64);
        ss += __shfl_xor(ss, 32, 64);
        zzr[mt] = ss;
    }
    __syncthreads();   // staging visible

    float m1[MT][4], m2[MT][4]; int i1[MT][4];
#pragma unroll
    for (int mt = 0; mt < MT; ++mt)
#pragma unroll
        for (int r = 0; r < 4; ++r) { m1[mt][r] = 1e30f; m2[mt][r] = 1e30f; i1[mt][r] = 0; }

#pragma unroll 4
    for (int t = 0; t < 32; ++t) {
        half8 B = *(const half8*)(lds_bf + t * 1024 + l * 16);
        float wwv = lds_ww[t * 16 + g16];
        int nl = t * 16 + g16;
#pragma unroll
        for (int mt = 0; mt < MT; ++mt) {
            f32x4 acc = {wwv, wwv, wwv, wwv};   // C-init = ||w||^2 -> acc = score
            acc = __builtin_amdgcn_mfma_f32_16x16x32_f16(A[mt], B, acc, 0, 0, 0);
#pragma unroll
            for (int r = 0; r < 4; ++r) {
                float s = acc[r];
                m2[mt][r] = fminf(m2[mt][r], fmaxf(s, m1[mt][r]));
                bool c = s < m1[mt][r];
                i1[mt][r] = c ? nl : i1[mt][r];
                m1[mt][r] = fminf(m1[mt][r], s);
            }
        }
    }

    // reduce (m1,m2,i1) across the 16 code-lanes of each row-group
#pragma unroll
    for (int mt = 0; mt < MT; ++mt)
#pragma unroll
        for (int r = 0; r < 4; ++r) {
            float a1v = m1[mt][r], a2v = m2[mt][r]; int ai = i1[mt][r];
#pragma unroll
            for (int dd = 1; dd <= 8; dd <<= 1) {
                float o1 = __shfl_xor(a1v, dd, 64);
                float o2 = __shfl_xor(a2v, dd, 64);
                int oi = __shfl_xor(ai, dd, 64);
                a2v = fminf(fminf(a2v, o2), fmaxf(a1v, o1));
                bool take = (o1 < a1v) || (o1 == a1v && oi < ai);
                ai = take ? oi : ai;
                a1v = fminf(a1v, o1);
            }
            m1[mt][r] = a1v; m2[mt][r] = a2v; i1[mt][r] = ai;
        }

    __syncthreads();   // all waves done reading bfrag/ww; safe to alias

    // row table (m1, m2, idx) + ||z||^2 table
#pragma unroll
    for (int mt = 0; mt < MT; ++mt) {
#pragma unroll
        for (int r = 0; r < 4; ++r)
            if (g16 == r) {
                int row = mt * 16 + 4 * kg + r;
                scratch[wv * 64 + row] =
                    make_float4(m1[mt][r], m2[mt][r], __int_as_float(i1[mt][r]), 0.f);
            }
        if (kg == 0) zzlds[wv * 64 + mt * 16 + g16] = zzr[mt];
    }
    __syncthreads();

    // near-tie rows: exact wave-parallel rescan (reference-quantized formula)
    float4 my = scratch[wv * 64 + l];
    unsigned long long mask = __ballot((my.y - my.x) <= MARGIN_TRIG);
    while (mask) {
        int row = __builtin_ctzll(mask); mask &= mask - 1;
        int v = vwave + row;
        const float* zv = z + (size_t)v * D;        // uniform addr -> broadcast
        double Ad = 0.0;
#pragma unroll
        for (int q = 0; q < 8; ++q) {
            float4 zzv = *(const float4*)(zv + q * 4);
            Ad = fma((double)zzv.x, (double)zzv.x, Ad);
            Ad = fma((double)zzv.y, (double)zzv.y, Ad);
            Ad = fma((double)zzv.z, (double)zzv.z, Ad);
            Ad = fma((double)zzv.w, (double)zzv.w, Ad);
        }
        float Af = (float)Ad;
        float best = 1e30f; int bi = 0;
#pragma unroll
        for (int j = 0; j < 8; ++j) {
            int c = l * 8 + j;                      // lane-major => index-ordered
            const float* w = cbf + (size_t)c * D;
            double bd = 0.0;
#pragma unroll
            for (int q = 0; q < 8; ++q) {
                float4 zzv = *(const float4*)(zv + q * 4);
                float4 wq = *(const float4*)(w + q * 4);
                bd = fma((double)zzv.x, (double)wq.x, bd);
                bd = fma((double)zzv.y, (double)wq.y, bd);
                bd = fma((double)zzv.z, (double)wq.z, bd);
                bd = fma((double)zzv.w, (double)wq.w, bd);
            }
            float B32 = (float)bd;
            float dq = __fadd_rn(__fsub_rn(Af, __fmul_rn(2.0f, B32)), c32g[c]);
            if (dq < best) { best = dq; bi = c; }
        }
#pragma unroll
        for (int dd = 1; dd < 64; dd <<= 1) {
            float ob = __shfl_xor(best, dd, 64);
            int obi = __shfl_xor(bi, dd, 64);
            bool take = (ob < best) || (ob == best && obi < bi);
            best = take ? ob : best; bi = take ? obi : bi;
        }
        if (l == 0) ((float*)&scratch[wv * 64 + row])[2] = __int_as_float(bi);
    }
    __syncthreads();

    // ---- epilogue ----
    // loss: ||z-q||^2 = ||z||^2 + s_win  (one row per lane)
    {
        float m1row = ((const float*)scratch)[(wv * 64 + l) * 4 + 0];
        float zzrow = zzlds[wv * 64 + l];
        double contrib = (double)m1row + (double)zzrow;
#pragma unroll
        for (int off = 32; off; off >>= 1) contrib += __shfl_down(contrib, off, 64);
        if (l == 0) atomicAdd(lossacc, contrib);
    }
    // indices: one row per lane, contiguous
    {
        int win = __float_as_int(((const float*)scratch)[(wv * 64 + l) * 4 + 2]);
        idxo[vwave + l] = (float)win;
    }
    // z_q: 8 lanes per row -> every store instruction covers 8 full 128B lines
    {
        const float4* cb4 = (const float4*)cbf;
        float4* zq4 = (float4*)zq;
        const int c = l & 7;
#pragma unroll
        for (int it = 0; it < 8; ++it) {
            int r = it * 8 + (l >> 3);
            int win = __float_as_int(((const float*)scratch)[(wv * 64 + r) * 4 + 2]);
            float4 val = cb4[(size_t)win * 8 + c];
            zq4[(size_t)(vwave + r) * 8 + c] = val;
        }
    }
}

__global__ void vq_final(const double* __restrict__ lossacc,
                         float* __restrict__ loss_out) {
    *loss_out = (float)(1.25 * (*lossacc) / (double)ZQ_ELEMS);
}

extern "C" void kernel_launch(void* const* d_in, const int* in_sizes, int n_in,
                              void* d_out, int out_size, void* d_ws, size_t ws_size,
                              hipStream_t stream) {
    const float* z  = (const float*)d_in[0];
    const float* cb = (const float*)d_in[1];
    float* out  = (float*)d_out;
    float* zq   = out;
    float* idxo = out + ZQ_ELEMS;
    float* loss = out + ZQ_ELEMS + NVEC;
    double* lossacc = (double*)d_ws;
    float*  ww      = (float*)((char*)d_ws + 64);
    half8*  bfrag   = (half8*)((char*)d_ws + 2112);
    const float4* stage_src = (const float4*)((char*)d_ws + 64);

    vq_prep<<<8, 256, 0, stream>>>(cb, ww, bfrag, lossacc);
    vq_main<<<NVEC / 256, 256, 0, stream>>>(z, cb, stage_src, ww, zq, idxo, lossacc);
    vq_final<<<1, 1, 0, stream>>>(lossacc, loss);
}

// Round 5
// 434.032 us; speedup vs baseline: 3.4228x; 1.8451x over previous
//
#include <hip/hip_runtime.h>

#define N_CODES 512
#define D 32
#define NVEC (8192 * 64)          // 524288 vectors
#define ZQ_ELEMS (NVEC * D)
#define MARGIN_TRIG 7e-5f
#define SA (-1.0f / 16.0f)        // A = SA*z   (power of 2, exact)
#define SB (32.0f)                // B = SB*w   -> A*B sums to -2 z.w

typedef _Float16 half8 __attribute__((ext_vector_type(8)));
typedef float f32x4 __attribute__((ext_vector_type(4)));

// ws: @0 double lossacc | @64 float ww[512] | @2112 half8 bfrag[32*64]
#define STAGE_F4 2176             // (2048 + 32768) / 16
// LDS: ww @0 (2048) | bfrag @2048 (32768) | scratch @34816 (4*64*16) = 38912 B

__global__ void vq_prep(const float* __restrict__ cb, float* __restrict__ ww,
                        half8* __restrict__ bfrag, double* __restrict__ lossacc) {
    int gid = blockIdx.x * 256 + threadIdx.x;   // 8 x 256 = 2048
    if (gid == 0) *lossacc = 0.0;
    if (gid >= 2048) return;
    int t = gid >> 6, l = gid & 63;
    int code = t * 16 + (l & 15), koff = (l >> 4) * 8;
    const float* w = cb + (size_t)code * D + koff;
    half8 h;
#pragma unroll
    for (int j = 0; j < 8; ++j) h[j] = (_Float16)(SB * w[j]);
    bfrag[t * 64 + l] = h;                      // MFMA B-fragment lane order
    if (koff == 0) {                            // platonic ||w||^2 -> f32
        const float* wr = cb + (size_t)code * D;
        double s = 0.0;
#pragma unroll
        for (int d = 0; d < D; ++d) s = fma((double)wr[d], (double)wr[d], s);
        ww[code] = (float)s;
    }
}

__global__ __launch_bounds__(256) void vq_main(
        const float* __restrict__ z, const float* __restrict__ cbf,
        const float4* __restrict__ stage_src,   // ws+64
        const float* __restrict__ c32g,         // ws+64 (ww)
        float* __restrict__ zq, float* __restrict__ idxo,
        double* __restrict__ lossacc) {
    __shared__ __align__(16) char smem[38912];
    const int tid = threadIdx.x;

    {   // stage ww + B-fragments into LDS
        float4* s4 = (float4*)smem;
#pragma unroll
        for (int i = 0; i < 9; ++i) {
            int k = i * 256 + tid;
            if (k < STAGE_F4) s4[k] = stage_src[k];
        }
    }

    const float* lds_ww = (const float*)smem;
    const char* lds_bf = smem + 2048;
    float4* scratch = (float4*)(smem + 34816);   // [4 waves][64 rows] (m1,m2,idx,zz)

    const int l = tid & 63, wv = tid >> 6;
    const int g16 = l & 15, kg = l >> 4, koff = kg * 8;
    const int vwave = blockIdx.x * 256 + wv * 64;   // wave owns 64 vectors

    __syncthreads();   // staging visible

    // one 16-row tile at a time: peak live state ~20 regs -> no spill
    for (int mt = 0; mt < 4; ++mt) {
        const float* zp = z + (size_t)(vwave + mt * 16 + g16) * D + koff;
        float4 a0 = *(const float4*)zp;
        float4 a1 = *(const float4*)(zp + 4);
        half8 A;
        A[0] = (_Float16)(a0.x * SA); A[1] = (_Float16)(a0.y * SA);
        A[2] = (_Float16)(a0.z * SA); A[3] = (_Float16)(a0.w * SA);
        A[4] = (_Float16)(a1.x * SA); A[5] = (_Float16)(a1.y * SA);
        A[6] = (_Float16)(a1.z * SA); A[7] = (_Float16)(a1.w * SA);
        float ss = 0.f;
        ss = fmaf(a0.x, a0.x, ss); ss = fmaf(a0.y, a0.y, ss);
        ss = fmaf(a0.z, a0.z, ss); ss = fmaf(a0.w, a0.w, ss);
        ss = fmaf(a1.x, a1.x, ss); ss = fmaf(a1.y, a1.y, ss);
        ss = fmaf(a1.z, a1.z, ss); ss = fmaf(a1.w, a1.w, ss);
        ss += __shfl_xor(ss, 16, 64);           // sum the 4 koff chunks
        ss += __shfl_xor(ss, 32, 64);

        float m1[4], m2[4]; int i1[4];
#pragma unroll
        for (int r = 0; r < 4; ++r) { m1[r] = 1e30f; m2[r] = 1e30f; i1[r] = 0; }

#pragma unroll 4
        for (int t = 0; t < 32; ++t) {
            half8 B = *(const half8*)(lds_bf + t * 1024 + l * 16);
            float wwv = lds_ww[t * 16 + g16];
            int nl = t * 16 + g16;
            f32x4 acc = {wwv, wwv, wwv, wwv};   // C-init = ||w||^2 -> acc = score
            acc = __builtin_amdgcn_mfma_f32_16x16x32_f16(A, B, acc, 0, 0, 0);
#pragma unroll
            for (int r = 0; r < 4; ++r) {
                float s = acc[r];
                m2[r] = fminf(m2[r], fmaxf(s, m1[r]));
                bool c = s < m1[r];
                i1[r] = c ? nl : i1[r];
                m1[r] = fminf(m1[r], s);
            }
        }

        // reduce across the 16 code-lanes of each row-group
#pragma unroll
        for (int r = 0; r < 4; ++r) {
            float a1v = m1[r], a2v = m2[r]; int ai = i1[r];
#pragma unroll
            for (int dd = 1; dd <= 8; dd <<= 1) {
                float o1 = __shfl_xor(a1v, dd, 64);
                float o2 = __shfl_xor(a2v, dd, 64);
                int oi = __shfl_xor(ai, dd, 64);
                a2v = fminf(fminf(a2v, o2), fmaxf(a1v, o1));
                bool take = (o1 < a1v) || (o1 == a1v && oi < ai);
                ai = take ? oi : ai;
                a1v = fminf(a1v, o1);
            }
            m1[r] = a1v; m2[r] = a2v; i1[r] = ai;
        }

        // write row table for this tile (results dead afterwards)
#pragma unroll
        for (int r = 0; r < 4; ++r)
            if (g16 == r) {
                float* sp = (float*)&scratch[wv * 64 + mt * 16 + 4 * kg + r];
                sp[0] = m1[r]; sp[1] = m2[r]; sp[2] = __int_as_float(i1[r]);
            }
        if (kg == 0)
            ((float*)&scratch[wv * 64 + mt * 16 + g16])[3] = ss;   // ||z||^2
    }
    __syncthreads();

    // near-tie rows: exact wave-parallel rescan (reference-quantized formula)
    float4 my = scratch[wv * 64 + l];
    unsigned long long mask = __ballot((my.y - my.x) <= MARGIN_TRIG);
    while (mask) {
        int row = __builtin_ctzll(mask); mask &= mask - 1;
        int v = vwave + row;
        const float* zv = z + (size_t)v * D;        // uniform addr -> broadcast
        double Ad = 0.0;
#pragma unroll
        for (int q = 0; q < 8; ++q) {
            float4 zzv = *(const float4*)(zv + q * 4);
            Ad = fma((double)zzv.x, (double)zzv.x, Ad);
            Ad = fma((double)zzv.y, (double)zzv.y, Ad);
            Ad = fma((double)zzv.z, (double)zzv.z, Ad);
            Ad = fma((double)zzv.w, (double)zzv.w, Ad);
        }
        float Af = (float)Ad;
        float best = 1e30f; int bi = 0;
#pragma unroll
        for (int j = 0; j < 8; ++j) {
            int c = l * 8 + j;                      // lane-major => index-ordered
            const float* w = cbf + (size_t)c * D;
            double bd = 0.0;
#pragma unroll
            for (int q = 0; q < 8; ++q) {
                float4 zzv = *(const float4*)(zv + q * 4);
                float4 wq = *(const float4*)(w + q * 4);
                bd = fma((double)zzv.x, (double)wq.x, bd);
                bd = fma((double)zzv.y, (double)wq.y, bd);
                bd = fma((double)zzv.z, (double)wq.z, bd);
                bd = fma((double)zzv.w, (double)wq.w, bd);
            }
            float B32 = (float)bd;
            float dq = __fadd_rn(__fsub_rn(Af, __fmul_rn(2.0f, B32)), c32g[c]);
            if (dq < best) { best = dq; bi = c; }
        }
#pragma unroll
        for (int dd = 1; dd < 64; dd <<= 1) {
            float ob = __shfl_xor(best, dd, 64);
            int obi = __shfl_xor(bi, dd, 64);
            bool take = (ob < best) || (ob == best && obi < bi);
            best = take ? ob : best; bi = take ? obi : bi;
        }
        if (l == 0) ((float*)&scratch[wv * 64 + row])[2] = __int_as_float(bi);
    }
    __syncthreads();

    // ---- epilogue ----
    // loss: ||z-q||^2 = ||z||^2 + s_win  (one row per lane)
    {
        const float* sp = (const float*)&scratch[wv * 64 + l];
        double contrib = (double)sp[0] + (double)sp[3];
#pragma unroll
        for (int off = 32; off; off >>= 1) contrib += __shfl_down(contrib, off, 64);
        if (l == 0) atomicAdd(lossacc, contrib);
    }
    // indices: one row per lane, contiguous
    {
        int win = __float_as_int(((const float*)scratch)[(wv * 64 + l) * 4 + 2]);
        idxo[vwave + l] = (float)win;
    }
    // z_q: 8 lanes per row -> every store instruction covers 8 full 128B lines
    {
        const float4* cb4 = (const float4*)cbf;
        float4* zq4 = (float4*)zq;
        const int c = l & 7;
#pragma unroll
        for (int it = 0; it < 8; ++it) {
            int r = it * 8 + (l >> 3);
            int win = __float_as_int(((const float*)scratch)[(wv * 64 + r) * 4 + 2]);
            float4 val = cb4[(size_t)win * 8 + c];
            zq4[(size_t)(vwave + r) * 8 + c] = val;
        }
    }
}

__global__ void vq_final(const double* __restrict__ lossacc,
                         float* __restrict__ loss_out) {
    *loss_out = (float)(1.25 * (*lossacc) / (double)ZQ_ELEMS);
}

extern "C" void kernel_launch(void* const* d_in, const int* in_sizes, int n_in,
                              void* d_out, int out_size, void* d_ws, size_t ws_size,
                              hipStream_t stream) {
    const float* z  = (const float*)d_in[0];
    const float* cb = (const float*)d_in[1];
    float* out  = (float*)d_out;
    float* zq   = out;
    float* idxo = out + ZQ_ELEMS;
    float* loss = out + ZQ_ELEMS + NVEC;
    double* lossacc = (double*)d_ws;
    float*  ww      = (float*)((char*)d_ws + 64);
    half8*  bfrag   = (half8*)((char*)d_ws + 2112);
    const float4* stage_src = (const float4*)((char*)d_ws + 64);

    vq_prep<<<8, 256, 0, stream>>>(cb, ww, bfrag, lossacc);
    vq_main<<<NVEC / 256, 256, 0, stream>>>(z, cb, stage_src, ww, zq, idxo, lossacc);
    vq_final<<<1, 1, 0, stream>>>(lossacc, loss);
}